// Round 6
// baseline (203.864 us; speedup 1.0000x reference)
//
#include <hip/hip_runtime.h>

typedef __bf16 bf16x8 __attribute__((ext_vector_type(8)));
typedef __bf16 bf16x4 __attribute__((ext_vector_type(4)));
typedef float f32x4 __attribute__((ext_vector_type(4)));
typedef float f32x16 __attribute__((ext_vector_type(16)));

#define MFMA_16x16x32(a, b, c) __builtin_amdgcn_mfma_f32_16x16x32_bf16((a), (b), (c), 0, 0, 0)
#define MFMA32(a, b, c) __builtin_amdgcn_mfma_f32_32x32x16_bf16((a), (b), (c), 0, 0, 0)

#define WAIT_LGKM0() do { \
    asm volatile("s_waitcnt lgkmcnt(0)" ::: "memory"); \
    __builtin_amdgcn_sched_barrier(0); } while (0)

// async global->LDS, 16B per lane; LDS dest must be wave-uniform base + lane*16
typedef const __attribute__((address_space(1))) void GVp;
typedef __attribute__((address_space(3))) void LVp;
#define GLOAD16(gp, lp) \
    __builtin_amdgcn_global_load_lds((GVp*)(gp), (LVp*)(lp), 16, 0, 0)

// 2^x via the HW transcendental (v_exp_f32 IS exp2 on gfx9) — avoids the
// glibc __exp2f macro collision that broke R5's compile.
__device__ __forceinline__ float fexp2(float x) {
    float r;
    asm("v_exp_f32 %0, %1" : "=v"(r) : "v"(x));
    return r;
}

// pack 2 f32 -> 2 bf16 (RNE) in one u32: low16 = lo, high16 = hi
__device__ __forceinline__ unsigned cvtpk(float lo, float hi) {
    unsigned r;
    asm("v_cvt_pk_bf16_f32 %0, %1, %2" : "=v"(r) : "v"(lo), "v"(hi));
    return r;
}
// swap: a.lanes[32:63] <-> b.lanes[0:31]
#define PSWAP(a, b) asm volatile("v_permlane32_swap_b32 %0, %1" : "+v"(a), "+v"(b))

union PB { unsigned u[4]; bf16x8 v; };

// XOR swizzle for row-major tiles with 128-byte rows
__device__ __forceinline__ int swz(int row, int colb) {
    return row * 128 + (colb ^ ((row & 7) << 4));
}

// ---------------- f32 -> bf16 conversions ----------------
__global__ __launch_bounds__(256) void cvt_f32_bf16(const float* __restrict__ in,
                                                    __bf16* __restrict__ out, int n4) {
    int i = blockIdx.x * 256 + threadIdx.x;
    if (i >= n4) return;
    float4 v = ((const float4*)in)[i];
    bf16x4 o;
    o[0] = (__bf16)v.x; o[1] = (__bf16)v.y; o[2] = (__bf16)v.z; o[3] = (__bf16)v.w;
    ((bf16x4*)out)[i] = o;
}

__global__ __launch_bounds__(256) void cvt_w4(const float* __restrict__ w0,
                                              const float* __restrict__ w1,
                                              const float* __restrict__ w2,
                                              const float* __restrict__ w3,
                                              __bf16* __restrict__ o0,
                                              __bf16* __restrict__ o1,
                                              __bf16* __restrict__ o2,
                                              __bf16* __restrict__ o3) {
    int z = blockIdx.y;
    const float* in = (z == 0) ? w0 : (z == 1) ? w1 : (z == 2) ? w2 : w3;
    __bf16* out = (z == 0) ? o0 : (z == 1) ? o1 : (z == 2) ? o2 : o3;
    int i = blockIdx.x * 256 + threadIdx.x;
    float4 v = ((const float4*)in)[i];
    bf16x4 o;
    o[0] = (__bf16)v.x; o[1] = (__bf16)v.y; o[2] = (__bf16)v.z; o[3] = (__bf16)v.w;
    ((bf16x4*)out)[i] = o;
}

// ---- GEMM body: C[M][N] = (A[M][K] * Bw[N][K]^T + bias[N]) * scale ----
// m97 structure: global_load_lds staging, linear LDS dest, inverse-swizzled
// global source + swizzled reads (rule #21). BN=128: 2x2 waves, 64x64 each.
// BN=64: 4x1 waves, 32x64 each. VT=true: write C^T per-batch (V^T) as
// C_T[b][n][t], b = row>>11.
template <typename OT, bool VT, int BN>
__device__ __forceinline__ void gemm_body(const __bf16* __restrict__ A,
                                          const __bf16* __restrict__ Bw,
                                          const float* __restrict__ bias,
                                          OT* __restrict__ C,
                                          int K, int N, float scale) {
    const int m0 = blockIdx.x * 128;
    const int n0 = blockIdx.y * BN;
    const int tid = threadIdx.x;
    const int l = tid & 63, w = tid >> 6;
    constexpr int MI = (BN == 128) ? 4 : 2;
    constexpr int WMS = (BN == 128) ? 64 : 32;
    const int wr = (BN == 128) ? (w >> 1) : w;
    const int wc = (BN == 128) ? (w & 1) : 0;
    const int lr = l & 15;
    const int lkb = (l >> 4) << 4;

    __shared__ __bf16 As[128 * 64];
    __shared__ __bf16 Bs[BN * 64];
    char* AsC = (char*)As;
    char* BsC = (char*)Bs;

    const int srow = tid >> 3;      // staging row within 32-row group
    const int scol8 = tid & 7;      // staging col group (8 elems)

    f32x4 acc[MI][4] = {};

    for (int k0 = 0; k0 < K; k0 += 64) {
        __syncthreads();
#pragma unroll
        for (int p = 0; p < 4; ++p) {
            int row = p * 32 + srow;
            int c8 = (scol8 ^ (row & 7)) * 8;  // inverse-swizzled source col
            GLOAD16(A + (size_t)(m0 + row) * K + k0 + c8, AsC + p * 4096 + tid * 16);
        }
#pragma unroll
        for (int p = 0; p < BN / 32; ++p) {
            int row = p * 32 + srow;
            int c8 = (scol8 ^ (row & 7)) * 8;
            GLOAD16(Bw + (size_t)(n0 + row) * K + k0 + c8, BsC + p * 4096 + tid * 16);
        }
        __syncthreads();  // compiler drains vmcnt before barrier -> tile ready
#pragma unroll
        for (int kk = 0; kk < 2; ++kk) {
            bf16x8 af[MI], bfr[4];
#pragma unroll
            for (int mi = 0; mi < MI; ++mi)
                af[mi] = *(const bf16x8*)(AsC + swz(wr * WMS + mi * 16 + lr, kk * 64 + lkb));
#pragma unroll
            for (int ni = 0; ni < 4; ++ni)
                bfr[ni] = *(const bf16x8*)(BsC + swz(wc * 64 + ni * 16 + lr, kk * 64 + lkb));
#pragma unroll
            for (int mi = 0; mi < MI; ++mi)
#pragma unroll
                for (int ni = 0; ni < 4; ++ni)
                    acc[mi][ni] = MFMA_16x16x32(af[mi], bfr[ni], acc[mi][ni]);
        }
    }

    const int rb = (l >> 4) * 4;
#pragma unroll
    for (int mi = 0; mi < MI; ++mi) {
#pragma unroll
        for (int ni = 0; ni < 4; ++ni) {
            int gn = n0 + wc * 64 + ni * 16 + lr;
            int gm = m0 + wr * WMS + mi * 16 + rb;
            float bv = bias[gn];
            if constexpr (VT) {
                bf16x4 o4;
#pragma unroll
                for (int j = 0; j < 4; ++j)
                    o4[j] = (__bf16)((acc[mi][ni][j] + bv) * scale);
                *(bf16x4*)((__bf16*)C + ((size_t)(gm >> 11) << 20) +
                           (size_t)gn * 2048 + (gm & 2047)) = o4;
            } else {
#pragma unroll
                for (int j = 0; j < 4; ++j) {
                    float v = (acc[mi][ni][j] + bv) * scale;
                    C[(size_t)(gm + j) * N + gn] = (OT)v;
                }
            }
        }
    }
}

// Q pre-scaled by 0.125 * log2(e): softmax runs in exp2 domain downstream.
#define QSCALE 0.18033688f

__global__ __launch_bounds__(256) void qkv_gemm(const __bf16* __restrict__ X,
                                                const __bf16* __restrict__ Wq,
                                                const __bf16* __restrict__ Wk,
                                                const __bf16* __restrict__ Wv,
                                                const float* __restrict__ bq,
                                                const float* __restrict__ bk,
                                                const float* __restrict__ bv,
                                                __bf16* __restrict__ Qo,
                                                __bf16* __restrict__ Ko,
                                                __bf16* __restrict__ Vto) {
    int z = blockIdx.z;
    if (z == 0) {
        gemm_body<__bf16, false, 128>(X, Wq, bq, Qo, 512, 512, QSCALE);
    } else if (z == 1) {
        gemm_body<__bf16, false, 128>(X, Wk, bk, Ko, 512, 512, 1.0f);
    } else {
        gemm_body<__bf16, true, 128>(X, Wv, bv, Vto, 512, 512, 1.0f);
    }
}

__global__ __launch_bounds__(256) void out_gemm(const __bf16* __restrict__ A,
                                                const __bf16* __restrict__ W,
                                                const float* __restrict__ bias,
                                                float* __restrict__ C) {
    gemm_body<float, false, 64>(A, W, bias, C, 512, 512, 1.0f);
}

// ---------------- flash attention forward, split-KV x2 ----------------
// grid (T/64, H, B*2): b = z>>1, half = z&1. 128 thr = 2 waves, wave owns
// 32 q-rows. Swapped QK^T (32x32x16), lane-local exp2 softmax, P in
// registers. K and V^T single-buffered in LDS (16.6 KB -> 8 blocks/CU).
// Emits locally-normalized partial O (bf16) + (m,l) per q-row per half.
__global__ __launch_bounds__(128, 4) void attn_fwd(const __bf16* __restrict__ Q,
                                                   const __bf16* __restrict__ K,
                                                   const __bf16* __restrict__ Vt,
                                                   __bf16* __restrict__ Op0,
                                                   __bf16* __restrict__ Op1,
                                                   float* __restrict__ ml) {
    const int T = 2048, Cm = 512;
    const int qt0 = blockIdx.x * 64;
    const int h = blockIdx.y;
    const int half = blockIdx.z & 1, b = blockIdx.z >> 1;
    const int kt0 = half * 1024;
    const int tid = threadIdx.x;
    const int l = tid & 63, w = tid >> 6;
    const int q5 = l & 31, hi = l >> 5;
    const size_t rbase = ((size_t)b * T) * Cm + h * 64;                 // Q,K
    const size_t vtbase = ((size_t)b << 20) + (size_t)(h * 64) * 2048;  // Vt

    // [0,8K): K tile; [8K,16K): V^T tile; [16K,16K+256): al scratch
    __shared__ __align__(16) char smem[16640];

    const int grow = tid >> 3;      // 0..15
    const int gc8 = (tid & 7) * 8;  // element col within 64
    const __bf16* kgp = K + rbase + (size_t)grow * Cm + gc8;
    const __bf16* vgp = Vt + vtbase + (size_t)grow * 2048 + gc8;
    int two[4];
#pragma unroll
    for (int p = 0; p < 4; ++p) two[p] = swz(grow + 16 * p, gc8 * 2);

    // Q fragments (B-operand): lane holds Q[q5][dc*16 + hi*8 + j]
    bf16x8 qf[4];
#pragma unroll
    for (int dc = 0; dc < 4; ++dc)
        qf[dc] = *(const bf16x8*)(Q + rbase +
            (size_t)(qt0 + w * 32 + q5) * Cm + dc * 16 + hi * 8);

    f32x16 oa[2] = {};
    float m_r = -1e30f, l_r = 0.f;

    // prologue: stage tile kt0
#pragma unroll
    for (int p = 0; p < 4; ++p) {
        int4 kv = *(const int4*)(kgp + (size_t)(kt0 + 16 * p) * Cm);
        int4 vv = *(const int4*)(vgp + (size_t)(16 * p) * 2048 + kt0);
        *(int4*)(smem + two[p]) = kv;
        *(int4*)(smem + 8192 + two[p]) = vv;
    }
    __syncthreads();

    char* albase = smem + 16384 + w * 128;

    for (int kt = kt0; kt < kt0 + 1024; kt += 64) {
        // T14: issue next tile's global loads early; LDS-write after PV
        int ktn = (kt + 64 < kt0 + 1024) ? kt + 64 : kt;
        int4 ks[4], vs[4];
#pragma unroll
        for (int p = 0; p < 4; ++p) {
            ks[p] = *(const int4*)(kgp + (size_t)(ktn + 16 * p) * Cm);
            vs[p] = *(const int4*)(vgp + (size_t)(16 * p) * 2048 + ktn);
        }

        // ---- S^T = K Q^T : lane holds S[q=q5][k = kb*32 + (r&3)+8*(r>>2)+4*hi]
        f32x16 s0 = {}, s1 = {};
#pragma unroll
        for (int dc = 0; dc < 4; ++dc) {
            bf16x8 kf0 = *(const bf16x8*)(smem + swz(q5, dc * 32 + hi * 16));
            bf16x8 kf1 = *(const bf16x8*)(smem + swz(32 + q5, dc * 32 + hi * 16));
            __builtin_amdgcn_s_setprio(1);
            s0 = MFMA32(kf0, qf[dc], s0);
            s1 = MFMA32(kf1, qf[dc], s1);
            __builtin_amdgcn_s_setprio(0);
        }

        // ---- in-lane softmax (exp2 domain) ----
        float t[16];
#pragma unroll
        for (int r = 0; r < 16; ++r) t[r] = fmaxf(s0[r], s1[r]);
#pragma unroll
        for (int d = 8; d >= 1; d >>= 1)
#pragma unroll
            for (int r = 0; r < d; ++r) t[r] = fmaxf(t[r], t[r + d]);
        float pm = fmaxf(t[0], __shfl_xor(t[0], 32));

        if (__any(pm - m_r > 11.5f)) {  // defer-max (2^11.5 ~ e^8)
            float mn = fmaxf(m_r, pm);
            float alv = fexp2(m_r - mn);
            m_r = mn;
            *(float*)(albase + q5 * 4) = alv;
            WAIT_LGKM0();
            f32x4 alr[4];
#pragma unroll
            for (int rg = 0; rg < 4; ++rg)
                alr[rg] = *(const f32x4*)(albase + hi * 16 + rg * 32);
#pragma unroll
            for (int r = 0; r < 16; ++r) {
                oa[0][r] *= alr[r >> 2][r & 3];
                oa[1][r] *= alr[r >> 2][r & 3];
            }
            l_r *= alv;
        }

        float rs = 0.f;
#pragma unroll
        for (int r = 0; r < 16; ++r) {
            float p0 = fexp2(s0[r] - m_r);
            float p1 = fexp2(s1[r] - m_r);
            s0[r] = p0; s1[r] = p1;
            rs += p0 + p1;
        }
        rs += __shfl_xor(rs, 32);
        l_r += rs;

        // ---- P -> bf16 PV A-frags in registers (16 cvt_pk + 8 permlane) ----
        PB pf[4];
#pragma unroll
        for (int kb = 0; kb < 2; ++kb) {
#pragma unroll
            for (int cc = 0; cc < 2; ++cc) {
                int gA = 8 * cc, gB = 8 * cc + 4;
                float a0, a1, a2, a3, b0, b1, b2, b3;
                if (kb == 0) {
                    a0 = s0[gA]; a1 = s0[gA + 1]; a2 = s0[gA + 2]; a3 = s0[gA + 3];
                    b0 = s0[gB]; b1 = s0[gB + 1]; b2 = s0[gB + 2]; b3 = s0[gB + 3];
                } else {
                    a0 = s1[gA]; a1 = s1[gA + 1]; a2 = s1[gA + 2]; a3 = s1[gA + 3];
                    b0 = s1[gB]; b1 = s1[gB + 1]; b2 = s1[gB + 2]; b3 = s1[gB + 3];
                }
                unsigned w0A = cvtpk(a0, a1), w1A = cvtpk(a2, a3);
                unsigned w0B = cvtpk(b0, b1), w1B = cvtpk(b2, b3);
                PSWAP(w0A, w0B);
                PSWAP(w1A, w1B);
                int kc = 2 * kb + cc;
                pf[kc].u[0] = w0A; pf[kc].u[1] = w1A;
                pf[kc].u[2] = w0B; pf[kc].u[3] = w1B;
            }
        }

        // ---- O += P V : B-frags from V^T tile (row = d, col = k) ----
#pragma unroll
        for (int kc = 0; kc < 4; ++kc) {
            bf16x8 vf0 = *(const bf16x8*)(smem + 8192 + swz(q5, kc * 32 + hi * 16));
            bf16x8 vf1 = *(const bf16x8*)(smem + 8192 + swz(32 + q5, kc * 32 + hi * 16));
            __builtin_amdgcn_s_setprio(1);
            oa[0] = MFMA32(pf[kc].v, vf0, oa[0]);
            oa[1] = MFMA32(pf[kc].v, vf1, oa[1]);
            __builtin_amdgcn_s_setprio(0);
        }

        // ---- single-buffer rotate: all reads done -> overwrite ----
        __syncthreads();
#pragma unroll
        for (int p = 0; p < 4; ++p) {
            *(int4*)(smem + two[p]) = ks[p];
            *(int4*)(smem + 8192 + two[p]) = vs[p];
        }
        __syncthreads();
    }

    // ---- epilogue: locally-normalized partial + (m,l) ----
    {
        float invl = 1.f / l_r;
        *(float*)(albase + q5 * 4) = invl;
        WAIT_LGKM0();
        f32x4 ivr[4];
#pragma unroll
        for (int rg = 0; rg < 4; ++rg)
            ivr[rg] = *(const f32x4*)(albase + hi * 16 + rg * 32);
        __bf16* Opb = half ? Op1 : Op0;
        const size_t rr = (size_t)(b * 8 + h) * 2048;
#pragma unroll
        for (int rg = 0; rg < 4; ++rg)
#pragma unroll
            for (int c = 0; c < 4; ++c) {
                int qr = qt0 + w * 32 + 8 * rg + 4 * hi + c;
                float iv = ivr[rg][c];
                Opb[(rr + qr) * 64 + q5]      = (__bf16)(oa[0][4 * rg + c] * iv);
                Opb[(rr + qr) * 64 + 32 + q5] = (__bf16)(oa[1][4 * rg + c] * iv);
            }
        if (hi == 0) {
            size_t mi_ = ((size_t)half * 65536 + rr + qt0 + w * 32 + q5) * 2;
            ml[mi_] = m_r;
            ml[mi_ + 1] = l_r;
        }
    }
}

// merge the two KV-halves: O = (w0*O0 + w1*O1), w_h ∝ l_h * 2^(m_h - M)
__global__ __launch_bounds__(256) void attn_merge(const __bf16* __restrict__ Op0,
                                                  const __bf16* __restrict__ Op1,
                                                  const float* __restrict__ ml,
                                                  __bf16* __restrict__ attnb) {
    const int NR = 65536;
    int r = blockIdx.x * 4 + (threadIdx.x >> 6);
    int d = threadIdx.x & 63;
    float m0 = ml[(size_t)r * 2], l0 = ml[(size_t)r * 2 + 1];
    float m1 = ml[((size_t)NR + r) * 2], l1 = ml[((size_t)NR + r) * 2 + 1];
    float M = fmaxf(m0, m1);
    float w0 = fexp2(m0 - M) * l0;
    float w1 = fexp2(m1 - M) * l1;
    float inv = 1.f / (w0 + w1);
    w0 *= inv; w1 *= inv;
    float o0 = (float)Op0[(size_t)r * 64 + d];
    float o1 = (float)Op1[(size_t)r * 64 + d];
    int q = r & 2047, bh = r >> 11, hh = bh & 7, bb = bh >> 3;
    attnb[((size_t)bb * 2048 + q) * 512 + hh * 64 + d] = (__bf16)(o0 * w0 + o1 * w1);
}

extern "C" void kernel_launch(void* const* d_in, const int* in_sizes, int n_in,
                              void* d_out, int out_size, void* d_ws, size_t ws_size,
                              hipStream_t stream) {
    const float* x  = (const float*)d_in[0];
    const float* wq = (const float*)d_in[1];
    const float* bq = (const float*)d_in[2];
    const float* wk = (const float*)d_in[3];
    const float* bk = (const float*)d_in[4];
    const float* wv = (const float*)d_in[5];
    const float* bv = (const float*)d_in[6];
    const float* wo = (const float*)d_in[7];
    const float* bo = (const float*)d_in[8];

    char* ws = (char*)d_ws;
    __bf16* xb    = (__bf16*)(ws);                       // 8 MiB; dead after qkv
    __bf16* Op0   = (__bf16*)(ws);                       // reuses xb region
    __bf16* Qb    = (__bf16*)(ws + ((size_t)8 << 20));
    __bf16* Kb    = (__bf16*)(ws + ((size_t)16 << 20));
    __bf16* Vtb   = (__bf16*)(ws + ((size_t)24 << 20));  // V^T [b][512][2048]
    __bf16* attnb = (__bf16*)(ws + ((size_t)32 << 20));
    __bf16* wqb   = (__bf16*)(ws + ((size_t)40 << 20));
    __bf16* wkb   = (__bf16*)(ws + ((size_t)40 << 20) + ((size_t)512 << 10));
    __bf16* wvb   = (__bf16*)(ws + ((size_t)40 << 20) + ((size_t)1024 << 10));
    __bf16* wob   = (__bf16*)(ws + ((size_t)40 << 20) + ((size_t)1536 << 10));
    __bf16* Op1   = (__bf16*)(ws + ((size_t)42 << 20));  // 8 MiB
    float*  mlb   = (float*)(ws + ((size_t)50 << 20));   // 1 MiB

    cvt_f32_bf16<<<dim3(4096), dim3(256), 0, stream>>>(x, xb, 1048576);
    cvt_w4<<<dim3(256, 4), dim3(256), 0, stream>>>(wq, wk, wv, wo,
                                                   wqb, wkb, wvb, wob);
    qkv_gemm<<<dim3(64, 4, 3), dim3(256), 0, stream>>>(xb, wqb, wkb, wvb,
                                                       bq, bk, bv, Qb, Kb, Vtb);
    attn_fwd<<<dim3(32, 8, 8), dim3(128), 0, stream>>>(Qb, Kb, Vtb, Op0, Op1, mlb);
    attn_merge<<<dim3(16384), dim3(256), 0, stream>>>(Op0, Op1, mlb, attnb);
    out_gemm<<<dim3(64, 8), dim3(256), 0, stream>>>(attnb, wob, bo, (float*)d_out);
}

// Round 7
// 203.365 us; speedup vs baseline: 1.0025x; 1.0025x over previous
//
#include <hip/hip_runtime.h>

typedef __bf16 bf16x8 __attribute__((ext_vector_type(8)));
typedef __bf16 bf16x4 __attribute__((ext_vector_type(4)));
typedef float f32x4 __attribute__((ext_vector_type(4)));
typedef float f32x16 __attribute__((ext_vector_type(16)));

#define MFMA_16x16x32(a, b, c) __builtin_amdgcn_mfma_f32_16x16x32_bf16((a), (b), (c), 0, 0, 0)
#define MFMA32(a, b, c) __builtin_amdgcn_mfma_f32_32x32x16_bf16((a), (b), (c), 0, 0, 0)

#define WAIT_LGKM0() do { \
    asm volatile("s_waitcnt lgkmcnt(0)" ::: "memory"); \
    __builtin_amdgcn_sched_barrier(0); } while (0)

// async global->LDS, 16B per lane; LDS dest must be wave-uniform base + lane*16
typedef const __attribute__((address_space(1))) void GVp;
typedef __attribute__((address_space(3))) void LVp;
#define GLOAD16(gp, lp) \
    __builtin_amdgcn_global_load_lds((GVp*)(gp), (LVp*)(lp), 16, 0, 0)

// 2^x via the HW transcendental (v_exp_f32 IS exp2 on gfx9) — avoids the
// glibc __exp2f macro collision.
__device__ __forceinline__ float fexp2(float x) {
    float r;
    asm("v_exp_f32 %0, %1" : "=v"(r) : "v"(x));
    return r;
}

// pack 2 f32 -> 2 bf16 (RNE) in one u32: low16 = lo, high16 = hi
__device__ __forceinline__ unsigned cvtpk(float lo, float hi) {
    unsigned r;
    asm("v_cvt_pk_bf16_f32 %0, %1, %2" : "=v"(r) : "v"(lo), "v"(hi));
    return r;
}
// swap: a.lanes[32:63] <-> b.lanes[0:31]
#define PSWAP(a, b) asm volatile("v_permlane32_swap_b32 %0, %1" : "+v"(a), "+v"(b))

union PB { unsigned u[4]; bf16x8 v; };

// XOR swizzle for row-major tiles with 128-byte rows
__device__ __forceinline__ int swz(int row, int colb) {
    return row * 128 + (colb ^ ((row & 7) << 4));
}

// ---------------- f32 -> bf16 conversions ----------------
__global__ __launch_bounds__(256) void cvt_f32_bf16(const float* __restrict__ in,
                                                    __bf16* __restrict__ out, int n4) {
    int i = blockIdx.x * 256 + threadIdx.x;
    if (i >= n4) return;
    float4 v = ((const float4*)in)[i];
    bf16x4 o;
    o[0] = (__bf16)v.x; o[1] = (__bf16)v.y; o[2] = (__bf16)v.z; o[3] = (__bf16)v.w;
    ((bf16x4*)out)[i] = o;
}

__global__ __launch_bounds__(256) void cvt_w4(const float* __restrict__ w0,
                                              const float* __restrict__ w1,
                                              const float* __restrict__ w2,
                                              const float* __restrict__ w3,
                                              __bf16* __restrict__ o0,
                                              __bf16* __restrict__ o1,
                                              __bf16* __restrict__ o2,
                                              __bf16* __restrict__ o3) {
    int z = blockIdx.y;
    const float* in = (z == 0) ? w0 : (z == 1) ? w1 : (z == 2) ? w2 : w3;
    __bf16* out = (z == 0) ? o0 : (z == 1) ? o1 : (z == 2) ? o2 : o3;
    int i = blockIdx.x * 256 + threadIdx.x;
    float4 v = ((const float4*)in)[i];
    bf16x4 o;
    o[0] = (__bf16)v.x; o[1] = (__bf16)v.y; o[2] = (__bf16)v.z; o[3] = (__bf16)v.w;
    ((bf16x4*)out)[i] = o;
}

// ---- GEMM body: C[M][N] = (A[M][K] * Bw[N][K]^T + bias[N]) * scale ----
// m97 structure: global_load_lds staging, linear LDS dest, inverse-swizzled
// global source + swizzled reads (rule #21). BN=128: 2x2 waves, 64x64 each.
// BN=64: 4x1 waves, 32x64 each. VT=true: write C^T per-batch (V^T) as
// C_T[b][n][t], b = row>>11.
template <typename OT, bool VT, int BN>
__device__ __forceinline__ void gemm_body(const __bf16* __restrict__ A,
                                          const __bf16* __restrict__ Bw,
                                          const float* __restrict__ bias,
                                          OT* __restrict__ C,
                                          int K, int N, float scale) {
    const int m0 = blockIdx.x * 128;
    const int n0 = blockIdx.y * BN;
    const int tid = threadIdx.x;
    const int l = tid & 63, w = tid >> 6;
    constexpr int MI = (BN == 128) ? 4 : 2;
    constexpr int WMS = (BN == 128) ? 64 : 32;
    const int wr = (BN == 128) ? (w >> 1) : w;
    const int wc = (BN == 128) ? (w & 1) : 0;
    const int lr = l & 15;
    const int lkb = (l >> 4) << 4;

    __shared__ __bf16 As[128 * 64];
    __shared__ __bf16 Bs[BN * 64];
    char* AsC = (char*)As;
    char* BsC = (char*)Bs;

    const int srow = tid >> 3;      // staging row within 32-row group
    const int scol8 = tid & 7;      // staging col group (8 elems)

    f32x4 acc[MI][4] = {};

    for (int k0 = 0; k0 < K; k0 += 64) {
        __syncthreads();
#pragma unroll
        for (int p = 0; p < 4; ++p) {
            int row = p * 32 + srow;
            int c8 = (scol8 ^ (row & 7)) * 8;  // inverse-swizzled source col
            GLOAD16(A + (size_t)(m0 + row) * K + k0 + c8, AsC + p * 4096 + tid * 16);
        }
#pragma unroll
        for (int p = 0; p < BN / 32; ++p) {
            int row = p * 32 + srow;
            int c8 = (scol8 ^ (row & 7)) * 8;
            GLOAD16(Bw + (size_t)(n0 + row) * K + k0 + c8, BsC + p * 4096 + tid * 16);
        }
        __syncthreads();  // compiler drains vmcnt before barrier -> tile ready
#pragma unroll
        for (int kk = 0; kk < 2; ++kk) {
            bf16x8 af[MI], bfr[4];
#pragma unroll
            for (int mi = 0; mi < MI; ++mi)
                af[mi] = *(const bf16x8*)(AsC + swz(wr * WMS + mi * 16 + lr, kk * 64 + lkb));
#pragma unroll
            for (int ni = 0; ni < 4; ++ni)
                bfr[ni] = *(const bf16x8*)(BsC + swz(wc * 64 + ni * 16 + lr, kk * 64 + lkb));
#pragma unroll
            for (int mi = 0; mi < MI; ++mi)
#pragma unroll
                for (int ni = 0; ni < 4; ++ni)
                    acc[mi][ni] = MFMA_16x16x32(af[mi], bfr[ni], acc[mi][ni]);
        }
    }

    const int rb = (l >> 4) * 4;
#pragma unroll
    for (int mi = 0; mi < MI; ++mi) {
#pragma unroll
        for (int ni = 0; ni < 4; ++ni) {
            int gn = n0 + wc * 64 + ni * 16 + lr;
            int gm = m0 + wr * WMS + mi * 16 + rb;
            float bv = bias[gn];
            if constexpr (VT) {
                bf16x4 o4;
#pragma unroll
                for (int j = 0; j < 4; ++j)
                    o4[j] = (__bf16)((acc[mi][ni][j] + bv) * scale);
                *(bf16x4*)((__bf16*)C + ((size_t)(gm >> 11) << 20) +
                           (size_t)gn * 2048 + (gm & 2047)) = o4;
            } else {
#pragma unroll
                for (int j = 0; j < 4; ++j) {
                    float v = (acc[mi][ni][j] + bv) * scale;
                    C[(size_t)(gm + j) * N + gn] = (OT)v;
                }
            }
        }
    }
}

// Q pre-scaled by 0.125 * log2(e): softmax runs in exp2 domain downstream.
#define QSCALE 0.18033688f

__global__ __launch_bounds__(256) void qkv_gemm(const __bf16* __restrict__ X,
                                                const __bf16* __restrict__ Wq,
                                                const __bf16* __restrict__ Wk,
                                                const __bf16* __restrict__ Wv,
                                                const float* __restrict__ bq,
                                                const float* __restrict__ bk,
                                                const float* __restrict__ bv,
                                                __bf16* __restrict__ Qo,
                                                __bf16* __restrict__ Ko,
                                                __bf16* __restrict__ Vto) {
    int z = blockIdx.z;
    if (z == 0) {
        gemm_body<__bf16, false, 128>(X, Wq, bq, Qo, 512, 512, QSCALE);
    } else if (z == 1) {
        gemm_body<__bf16, false, 128>(X, Wk, bk, Ko, 512, 512, 1.0f);
    } else {
        gemm_body<__bf16, true, 128>(X, Wv, bv, Vto, 512, 512, 1.0f);
    }
}

__global__ __launch_bounds__(256) void out_gemm(const __bf16* __restrict__ A,
                                                const __bf16* __restrict__ W,
                                                const float* __restrict__ bias,
                                                float* __restrict__ C) {
    gemm_body<float, false, 64>(A, W, bias, C, 512, 512, 1.0f);
}

// ---------------- flash attention forward, split-KV x2 ----------------
// grid (T/64, H, B*2): b = z>>1, half = z&1. 128 thr = 2 waves, wave owns
// 32 q-rows. Swapped QK^T (32x32x16), lane-local exp2 softmax, P in
// registers. K and V^T single-buffered in LDS (16.6 KB).
// __launch_bounds__(128, 2): min-waves=4 capped the unified VGPR/AGPR file
// at ~128 in R6 and spilled ~450 MB/launch to scratch (WRITE_SIZE 470 MB,
// VGPR_Count 64). At 2 the body fits (~90 VGPR, R4 evidence) and HW still
// co-resides 4 waves/SIMD when regs <= 128.
__global__ __launch_bounds__(128, 2) void attn_fwd(const __bf16* __restrict__ Q,
                                                   const __bf16* __restrict__ K,
                                                   const __bf16* __restrict__ Vt,
                                                   __bf16* __restrict__ Op0,
                                                   __bf16* __restrict__ Op1,
                                                   float* __restrict__ ml) {
    const int T = 2048, Cm = 512;
    const int qt0 = blockIdx.x * 64;
    const int h = blockIdx.y;
    const int half = blockIdx.z & 1, b = blockIdx.z >> 1;
    const int kt0 = half * 1024;
    const int tid = threadIdx.x;
    const int l = tid & 63, w = tid >> 6;
    const int q5 = l & 31, hi = l >> 5;
    const size_t rbase = ((size_t)b * T) * Cm + h * 64;                 // Q,K
    const size_t vtbase = ((size_t)b << 20) + (size_t)(h * 64) * 2048;  // Vt

    // [0,8K): K tile; [8K,16K): V^T tile; [16K,16K+256): al scratch
    __shared__ __align__(16) char smem[16640];

    const int grow = tid >> 3;      // 0..15
    const int gc8 = (tid & 7) * 8;  // element col within 64
    const __bf16* kgp = K + rbase + (size_t)grow * Cm + gc8;
    const __bf16* vgp = Vt + vtbase + (size_t)grow * 2048 + gc8;
    int two[4];
#pragma unroll
    for (int p = 0; p < 4; ++p) two[p] = swz(grow + 16 * p, gc8 * 2);

    // Q fragments (B-operand): lane holds Q[q5][dc*16 + hi*8 + j]
    bf16x8 qf[4];
#pragma unroll
    for (int dc = 0; dc < 4; ++dc)
        qf[dc] = *(const bf16x8*)(Q + rbase +
            (size_t)(qt0 + w * 32 + q5) * Cm + dc * 16 + hi * 8);

    f32x16 oa[2] = {};
    float m_r = -1e30f, l_r = 0.f;

    // prologue: stage tile kt0
#pragma unroll
    for (int p = 0; p < 4; ++p) {
        int4 kv = *(const int4*)(kgp + (size_t)(kt0 + 16 * p) * Cm);
        int4 vv = *(const int4*)(vgp + (size_t)(16 * p) * 2048 + kt0);
        *(int4*)(smem + two[p]) = kv;
        *(int4*)(smem + 8192 + two[p]) = vv;
    }
    __syncthreads();

    char* albase = smem + 16384 + w * 128;

    for (int kt = kt0; kt < kt0 + 1024; kt += 64) {
        // T14: issue next tile's global loads early; LDS-write after PV
        int ktn = (kt + 64 < kt0 + 1024) ? kt + 64 : kt;
        int4 ks[4], vs[4];
#pragma unroll
        for (int p = 0; p < 4; ++p) {
            ks[p] = *(const int4*)(kgp + (size_t)(ktn + 16 * p) * Cm);
            vs[p] = *(const int4*)(vgp + (size_t)(16 * p) * 2048 + ktn);
        }

        // ---- S^T = K Q^T : lane holds S[q=q5][k = kb*32 + (r&3)+8*(r>>2)+4*hi]
        f32x16 s0 = {}, s1 = {};
#pragma unroll
        for (int dc = 0; dc < 4; ++dc) {
            bf16x8 kf0 = *(const bf16x8*)(smem + swz(q5, dc * 32 + hi * 16));
            bf16x8 kf1 = *(const bf16x8*)(smem + swz(32 + q5, dc * 32 + hi * 16));
            __builtin_amdgcn_s_setprio(1);
            s0 = MFMA32(kf0, qf[dc], s0);
            s1 = MFMA32(kf1, qf[dc], s1);
            __builtin_amdgcn_s_setprio(0);
        }

        // ---- in-lane softmax (exp2 domain) ----
        float t[16];
#pragma unroll
        for (int r = 0; r < 16; ++r) t[r] = fmaxf(s0[r], s1[r]);
#pragma unroll
        for (int d = 8; d >= 1; d >>= 1)
#pragma unroll
            for (int r = 0; r < d; ++r) t[r] = fmaxf(t[r], t[r + d]);
        float pm = fmaxf(t[0], __shfl_xor(t[0], 32));

        if (__any(pm - m_r > 11.5f)) {  // defer-max (2^11.5 ~ e^8)
            float mn = fmaxf(m_r, pm);
            float alv = fexp2(m_r - mn);
            m_r = mn;
            *(float*)(albase + q5 * 4) = alv;
            WAIT_LGKM0();
            f32x4 alr[4];
#pragma unroll
            for (int rg = 0; rg < 4; ++rg)
                alr[rg] = *(const f32x4*)(albase + hi * 16 + rg * 32);
#pragma unroll
            for (int r = 0; r < 16; ++r) {
                oa[0][r] *= alr[r >> 2][r & 3];
                oa[1][r] *= alr[r >> 2][r & 3];
            }
            l_r *= alv;
        }

        float rs = 0.f;
#pragma unroll
        for (int r = 0; r < 16; ++r) {
            float p0 = fexp2(s0[r] - m_r);
            float p1 = fexp2(s1[r] - m_r);
            s0[r] = p0; s1[r] = p1;
            rs += p0 + p1;
        }
        rs += __shfl_xor(rs, 32);
        l_r += rs;

        // ---- P -> bf16 PV A-frags in registers (16 cvt_pk + 8 permlane) ----
        PB pf[4];
#pragma unroll
        for (int kb = 0; kb < 2; ++kb) {
#pragma unroll
            for (int cc = 0; cc < 2; ++cc) {
                int gA = 8 * cc, gB = 8 * cc + 4;
                float a0, a1, a2, a3, b0, b1, b2, b3;
                if (kb == 0) {
                    a0 = s0[gA]; a1 = s0[gA + 1]; a2 = s0[gA + 2]; a3 = s0[gA + 3];
                    b0 = s0[gB]; b1 = s0[gB + 1]; b2 = s0[gB + 2]; b3 = s0[gB + 3];
                } else {
                    a0 = s1[gA]; a1 = s1[gA + 1]; a2 = s1[gA + 2]; a3 = s1[gA + 3];
                    b0 = s1[gB]; b1 = s1[gB + 1]; b2 = s1[gB + 2]; b3 = s1[gB + 3];
                }
                unsigned w0A = cvtpk(a0, a1), w1A = cvtpk(a2, a3);
                unsigned w0B = cvtpk(b0, b1), w1B = cvtpk(b2, b3);
                PSWAP(w0A, w0B);
                PSWAP(w1A, w1B);
                int kc = 2 * kb + cc;
                pf[kc].u[0] = w0A; pf[kc].u[1] = w1A;
                pf[kc].u[2] = w0B; pf[kc].u[3] = w1B;
            }
        }

        // ---- O += P V : B-frags from V^T tile (row = d, col = k) ----
#pragma unroll
        for (int kc = 0; kc < 4; ++kc) {
            bf16x8 vf0 = *(const bf16x8*)(smem + 8192 + swz(q5, kc * 32 + hi * 16));
            bf16x8 vf1 = *(const bf16x8*)(smem + 8192 + swz(32 + q5, kc * 32 + hi * 16));
            __builtin_amdgcn_s_setprio(1);
            oa[0] = MFMA32(pf[kc].v, vf0, oa[0]);
            oa[1] = MFMA32(pf[kc].v, vf1, oa[1]);
            __builtin_amdgcn_s_setprio(0);
        }

        // ---- single-buffer rotate: all reads done -> overwrite ----
        __syncthreads();
#pragma unroll
        for (int p = 0; p < 4; ++p) {
            *(int4*)(smem + two[p]) = ks[p];
            *(int4*)(smem + 8192 + two[p]) = vs[p];
        }
        __syncthreads();
    }

    // ---- epilogue: locally-normalized partial + (m,l) ----
    {
        float invl = 1.f / l_r;
        *(float*)(albase + q5 * 4) = invl;
        WAIT_LGKM0();
        f32x4 ivr[4];
#pragma unroll
        for (int rg = 0; rg < 4; ++rg)
            ivr[rg] = *(const f32x4*)(albase + hi * 16 + rg * 32);
        __bf16* Opb = half ? Op1 : Op0;
        const size_t rr = (size_t)(b * 8 + h) * 2048;
#pragma unroll
        for (int rg = 0; rg < 4; ++rg)
#pragma unroll
            for (int c = 0; c < 4; ++c) {
                int qr = qt0 + w * 32 + 8 * rg + 4 * hi + c;
                float iv = ivr[rg][c];
                Opb[(rr + qr) * 64 + q5]      = (__bf16)(oa[0][4 * rg + c] * iv);
                Opb[(rr + qr) * 64 + 32 + q5] = (__bf16)(oa[1][4 * rg + c] * iv);
            }
        if (hi == 0) {
            size_t mi_ = ((size_t)half * 65536 + rr + qt0 + w * 32 + q5) * 2;
            ml[mi_] = m_r;
            ml[mi_ + 1] = l_r;
        }
    }
}

// merge the two KV-halves: O = (w0*O0 + w1*O1), w_h ∝ l_h * 2^(m_h - M)
__global__ __launch_bounds__(256) void attn_merge(const __bf16* __restrict__ Op0,
                                                  const __bf16* __restrict__ Op1,
                                                  const float* __restrict__ ml,
                                                  __bf16* __restrict__ attnb) {
    const int NR = 65536;
    int r = blockIdx.x * 4 + (threadIdx.x >> 6);
    int d = threadIdx.x & 63;
    float m0 = ml[(size_t)r * 2], l0 = ml[(size_t)r * 2 + 1];
    float m1 = ml[((size_t)NR + r) * 2], l1 = ml[((size_t)NR + r) * 2 + 1];
    float M = fmaxf(m0, m1);
    float w0 = fexp2(m0 - M) * l0;
    float w1 = fexp2(m1 - M) * l1;
    float inv = 1.f / (w0 + w1);
    w0 *= inv; w1 *= inv;
    float o0 = (float)Op0[(size_t)r * 64 + d];
    float o1 = (float)Op1[(size_t)r * 64 + d];
    int q = r & 2047, bh = r >> 11, hh = bh & 7, bb = bh >> 3;
    attnb[((size_t)bb * 2048 + q) * 512 + hh * 64 + d] = (__bf16)(o0 * w0 + o1 * w1);
}

extern "C" void kernel_launch(void* const* d_in, const int* in_sizes, int n_in,
                              void* d_out, int out_size, void* d_ws, size_t ws_size,
                              hipStream_t stream) {
    const float* x  = (const float*)d_in[0];
    const float* wq = (const float*)d_in[1];
    const float* bq = (const float*)d_in[2];
    const float* wk = (const float*)d_in[3];
    const float* bk = (const float*)d_in[4];
    const float* wv = (const float*)d_in[5];
    const float* bv = (const float*)d_in[6];
    const float* wo = (const float*)d_in[7];
    const float* bo = (const float*)d_in[8];

    char* ws = (char*)d_ws;
    __bf16* xb    = (__bf16*)(ws);                       // 8 MiB; dead after qkv
    __bf16* Op0   = (__bf16*)(ws);                       // reuses xb region
    __bf16* Qb    = (__bf16*)(ws + ((size_t)8 << 20));
    __bf16* Kb    = (__bf16*)(ws + ((size_t)16 << 20));
    __bf16* Vtb   = (__bf16*)(ws + ((size_t)24 << 20));  // V^T [b][512][2048]
    __bf16* attnb = (__bf16*)(ws + ((size_t)32 << 20));
    __bf16* wqb   = (__bf16*)(ws + ((size_t)40 << 20));
    __bf16* wkb   = (__bf16*)(ws + ((size_t)40 << 20) + ((size_t)512 << 10));
    __bf16* wvb   = (__bf16*)(ws + ((size_t)40 << 20) + ((size_t)1024 << 10));
    __bf16* wob   = (__bf16*)(ws + ((size_t)40 << 20) + ((size_t)1536 << 10));
    __bf16* Op1   = (__bf16*)(ws + ((size_t)42 << 20));  // 8 MiB
    float*  mlb   = (float*)(ws + ((size_t)50 << 20));   // 1 MiB

    cvt_f32_bf16<<<dim3(4096), dim3(256), 0, stream>>>(x, xb, 1048576);
    cvt_w4<<<dim3(256, 4), dim3(256), 0, stream>>>(wq, wk, wv, wo,
                                                   wqb, wkb, wvb, wob);
    qkv_gemm<<<dim3(64, 4, 3), dim3(256), 0, stream>>>(xb, wqb, wkb, wvb,
                                                       bq, bk, bv, Qb, Kb, Vtb);
    attn_fwd<<<dim3(32, 8, 8), dim3(128), 0, stream>>>(Qb, Kb, Vtb, Op0, Op1, mlb);
    attn_merge<<<dim3(16384), dim3(256), 0, stream>>>(Op0, Op1, mlb, attnb);
    out_gemm<<<dim3(64, 8), dim3(256), 0, stream>>>(attnb, wob, bo, (float*)d_out);
}

// Round 8
// 120.306 us; speedup vs baseline: 1.6946x; 1.6904x over previous
//
#include <hip/hip_runtime.h>

typedef __bf16 bf16x8 __attribute__((ext_vector_type(8)));
typedef __bf16 bf16x4 __attribute__((ext_vector_type(4)));
typedef float f32x4 __attribute__((ext_vector_type(4)));
typedef float f32x16 __attribute__((ext_vector_type(16)));

#define MFMA_16x16x32(a, b, c) __builtin_amdgcn_mfma_f32_16x16x32_bf16((a), (b), (c), 0, 0, 0)
#define MFMA32(a, b, c) __builtin_amdgcn_mfma_f32_32x32x16_bf16((a), (b), (c), 0, 0, 0)

#define WAIT_LGKM0() do { \
    asm volatile("s_waitcnt lgkmcnt(0)" ::: "memory"); \
    __builtin_amdgcn_sched_barrier(0); } while (0)

// async global->LDS, 16B per lane; LDS dest must be wave-uniform base + lane*16
typedef const __attribute__((address_space(1))) void GVp;
typedef __attribute__((address_space(3))) void LVp;
#define GLOAD16(gp, lp) \
    __builtin_amdgcn_global_load_lds((GVp*)(gp), (LVp*)(lp), 16, 0, 0)

// 2^x via the HW transcendental (v_exp_f32 IS exp2 on gfx9) — avoids the
// glibc __exp2f macro collision.
__device__ __forceinline__ float fexp2(float x) {
    float r;
    asm("v_exp_f32 %0, %1" : "=v"(r) : "v"(x));
    return r;
}

// pack 2 f32 -> 2 bf16 (RNE) in one u32: low16 = lo, high16 = hi
__device__ __forceinline__ unsigned cvtpk(float lo, float hi) {
    unsigned r;
    asm("v_cvt_pk_bf16_f32 %0, %1, %2" : "=v"(r) : "v"(lo), "v"(hi));
    return r;
}
// swap: a.lanes[32:63] <-> b.lanes[0:31]
#define PSWAP(a, b) asm volatile("v_permlane32_swap_b32 %0, %1" : "+v"(a), "+v"(b))

union PB { unsigned u[4]; bf16x8 v; };

// XOR swizzle for row-major tiles with 128-byte rows
__device__ __forceinline__ int swz(int row, int colb) {
    return row * 128 + (colb ^ ((row & 7) << 4));
}

// ---------------- f32 -> bf16 conversions ----------------
__global__ __launch_bounds__(256) void cvt_f32_bf16(const float* __restrict__ in,
                                                    __bf16* __restrict__ out, int n4) {
    int i = blockIdx.x * 256 + threadIdx.x;
    if (i >= n4) return;
    float4 v = ((const float4*)in)[i];
    bf16x4 o;
    o[0] = (__bf16)v.x; o[1] = (__bf16)v.y; o[2] = (__bf16)v.z; o[3] = (__bf16)v.w;
    ((bf16x4*)out)[i] = o;
}

__global__ __launch_bounds__(256) void cvt_w4(const float* __restrict__ w0,
                                              const float* __restrict__ w1,
                                              const float* __restrict__ w2,
                                              const float* __restrict__ w3,
                                              __bf16* __restrict__ o0,
                                              __bf16* __restrict__ o1,
                                              __bf16* __restrict__ o2,
                                              __bf16* __restrict__ o3) {
    int z = blockIdx.y;
    const float* in = (z == 0) ? w0 : (z == 1) ? w1 : (z == 2) ? w2 : w3;
    __bf16* out = (z == 0) ? o0 : (z == 1) ? o1 : (z == 2) ? o2 : o3;
    int i = blockIdx.x * 256 + threadIdx.x;
    float4 v = ((const float4*)in)[i];
    bf16x4 o;
    o[0] = (__bf16)v.x; o[1] = (__bf16)v.y; o[2] = (__bf16)v.z; o[3] = (__bf16)v.w;
    ((bf16x4*)out)[i] = o;
}

// ---- GEMM body: C[M][N] = (A[M][K] * Bw[N][K]^T + bias[N]) * scale ----
// m97 structure: global_load_lds staging, linear LDS dest, inverse-swizzled
// global source + swizzled reads (rule #21). BN=128: 2x2 waves, 64x64 each.
// BN=64: 4x1 waves, 32x64 each. VT=true: write C^T per-batch (V^T) as
// C_T[b][n][t], b = row>>11.
template <typename OT, bool VT, int BN>
__device__ __forceinline__ void gemm_body(const __bf16* __restrict__ A,
                                          const __bf16* __restrict__ Bw,
                                          const float* __restrict__ bias,
                                          OT* __restrict__ C,
                                          int K, int N, float scale) {
    const int m0 = blockIdx.x * 128;
    const int n0 = blockIdx.y * BN;
    const int tid = threadIdx.x;
    const int l = tid & 63, w = tid >> 6;
    constexpr int MI = (BN == 128) ? 4 : 2;
    constexpr int WMS = (BN == 128) ? 64 : 32;
    const int wr = (BN == 128) ? (w >> 1) : w;
    const int wc = (BN == 128) ? (w & 1) : 0;
    const int lr = l & 15;
    const int lkb = (l >> 4) << 4;

    __shared__ __bf16 As[128 * 64];
    __shared__ __bf16 Bs[BN * 64];
    char* AsC = (char*)As;
    char* BsC = (char*)Bs;

    const int srow = tid >> 3;      // staging row within 32-row group
    const int scol8 = tid & 7;      // staging col group (8 elems)

    f32x4 acc[MI][4] = {};

    for (int k0 = 0; k0 < K; k0 += 64) {
        __syncthreads();
#pragma unroll
        for (int p = 0; p < 4; ++p) {
            int row = p * 32 + srow;
            int c8 = (scol8 ^ (row & 7)) * 8;  // inverse-swizzled source col
            GLOAD16(A + (size_t)(m0 + row) * K + k0 + c8, AsC + p * 4096 + tid * 16);
        }
#pragma unroll
        for (int p = 0; p < BN / 32; ++p) {
            int row = p * 32 + srow;
            int c8 = (scol8 ^ (row & 7)) * 8;
            GLOAD16(Bw + (size_t)(n0 + row) * K + k0 + c8, BsC + p * 4096 + tid * 16);
        }
        __syncthreads();  // compiler drains vmcnt before barrier -> tile ready
#pragma unroll
        for (int kk = 0; kk < 2; ++kk) {
            bf16x8 af[MI], bfr[4];
#pragma unroll
            for (int mi = 0; mi < MI; ++mi)
                af[mi] = *(const bf16x8*)(AsC + swz(wr * WMS + mi * 16 + lr, kk * 64 + lkb));
#pragma unroll
            for (int ni = 0; ni < 4; ++ni)
                bfr[ni] = *(const bf16x8*)(BsC + swz(wc * 64 + ni * 16 + lr, kk * 64 + lkb));
#pragma unroll
            for (int mi = 0; mi < MI; ++mi)
#pragma unroll
                for (int ni = 0; ni < 4; ++ni)
                    acc[mi][ni] = MFMA_16x16x32(af[mi], bfr[ni], acc[mi][ni]);
        }
    }

    const int rb = (l >> 4) * 4;
#pragma unroll
    for (int mi = 0; mi < MI; ++mi) {
#pragma unroll
        for (int ni = 0; ni < 4; ++ni) {
            int gn = n0 + wc * 64 + ni * 16 + lr;
            int gm = m0 + wr * WMS + mi * 16 + rb;
            float bv = bias[gn];
            if constexpr (VT) {
                bf16x4 o4;
#pragma unroll
                for (int j = 0; j < 4; ++j)
                    o4[j] = (__bf16)((acc[mi][ni][j] + bv) * scale);
                *(bf16x4*)((__bf16*)C + ((size_t)(gm >> 11) << 20) +
                           (size_t)gn * 2048 + (gm & 2047)) = o4;
            } else {
#pragma unroll
                for (int j = 0; j < 4; ++j) {
                    float v = (acc[mi][ni][j] + bv) * scale;
                    C[(size_t)(gm + j) * N + gn] = (OT)v;
                }
            }
        }
    }
}

// Q pre-scaled by 0.125 * log2(e): softmax runs in exp2 domain downstream.
#define QSCALE 0.18033688f

__global__ __launch_bounds__(256) void qkv_gemm(const __bf16* __restrict__ X,
                                                const __bf16* __restrict__ Wq,
                                                const __bf16* __restrict__ Wk,
                                                const __bf16* __restrict__ Wv,
                                                const float* __restrict__ bq,
                                                const float* __restrict__ bk,
                                                const float* __restrict__ bv,
                                                __bf16* __restrict__ Qo,
                                                __bf16* __restrict__ Ko,
                                                __bf16* __restrict__ Vto) {
    int z = blockIdx.z;
    if (z == 0) {
        gemm_body<__bf16, false, 128>(X, Wq, bq, Qo, 512, 512, QSCALE);
    } else if (z == 1) {
        gemm_body<__bf16, false, 128>(X, Wk, bk, Ko, 512, 512, 1.0f);
    } else {
        gemm_body<__bf16, true, 128>(X, Wv, bv, Vto, 512, 512, 1.0f);
    }
}

__global__ __launch_bounds__(256) void out_gemm(const __bf16* __restrict__ A,
                                                const __bf16* __restrict__ W,
                                                const float* __restrict__ bias,
                                                float* __restrict__ C) {
    gemm_body<float, false, 64>(A, W, bias, C, 512, 512, 1.0f);
}

// ---------------- flash attention forward, split-KV x2 ----------------
// grid (T/64, H, B*2): b = z>>1, half = z&1. 128 thr = 2 waves, wave owns
// 32 q-rows. Swapped QK^T (32x32x16), lane-local exp2 softmax, P in
// registers. K and V^T double-buffered in LDS via global_load_lds (async
// DMA, no data registers) — R6/R7's reg-staged prefetch (ks[4]/vs[4], 32
// VGPRs live across the asm-softmax peak) was being spilled to scratch
// (~450 MB/dispatch, WRITE_SIZE 470 MB). Source addr carries the inverse
// swizzle; reads use swz() (rule #21). Barrier's implicit vmcnt(0) drain
// guarantees the prefetched buffer is complete.
__global__ __launch_bounds__(128, 2) void attn_fwd(const __bf16* __restrict__ Q,
                                                   const __bf16* __restrict__ K,
                                                   const __bf16* __restrict__ Vt,
                                                   __bf16* __restrict__ Op0,
                                                   __bf16* __restrict__ Op1,
                                                   float* __restrict__ ml) {
    const int T = 2048, Cm = 512;
    const int qt0 = blockIdx.x * 64;
    const int h = blockIdx.y;
    const int half = blockIdx.z & 1, b = blockIdx.z >> 1;
    const int kt0 = half * 1024, kend = kt0 + 1024;
    const int tid = threadIdx.x;
    const int l = tid & 63, w = tid >> 6;
    const int q5 = l & 31, hi = l >> 5;
    const size_t rbase = ((size_t)b * T) * Cm + h * 64;                 // Q,K
    const size_t vtbase = ((size_t)b << 20) + (size_t)(h * 64) * 2048;  // Vt

    // [0,16K): K dbuf; [16K,32K): V^T dbuf; [32K,32K+256): al scratch
    __shared__ __align__(16) char smem[33024];

    // staging: pass p covers rows p*16+grow, 16B per lane, linear LDS dest
    const int grow = tid >> 3;                       // 0..15
    const int gcol = ((tid & 7) ^ (grow & 7)) * 8;   // inverse-swizzled col
    const __bf16* kgp = K + rbase + (size_t)grow * Cm + gcol;
    const __bf16* vgp = Vt + vtbase + (size_t)grow * 2048 + gcol;

#define ATTN_STAGE(nb, ktv)                                                   \
    do {                                                                      \
        char* kd_ = smem + (nb) * 8192 + tid * 16;                            \
        char* vd_ = smem + 16384 + (nb) * 8192 + tid * 16;                    \
        _Pragma("unroll")                                                     \
        for (int p = 0; p < 4; ++p) {                                         \
            GLOAD16(kgp + (size_t)((ktv) + p * 16) * Cm, kd_ + p * 2048);     \
            GLOAD16(vgp + (size_t)(p * 16) * 2048 + (ktv), vd_ + p * 2048);   \
        }                                                                     \
    } while (0)

    // Q fragments (B-operand): lane holds Q[q5][dc*16 + hi*8 + j]
    bf16x8 qf[4];
#pragma unroll
    for (int dc = 0; dc < 4; ++dc)
        qf[dc] = *(const bf16x8*)(Q + rbase +
            (size_t)(qt0 + w * 32 + q5) * Cm + dc * 16 + hi * 8);

    f32x16 oa[2] = {};
    float m_r = -1e30f, l_r = 0.f;

    // prologue: stage tile kt0 into buffer 0
    ATTN_STAGE(0, kt0);
    __syncthreads();

    char* albase = smem + 32768 + w * 128;

    int cur = 0;
    for (int kt = kt0; kt < kend; kt += 64, cur ^= 1) {
        // async prefetch of next tile into the other buffer (no registers)
        if (kt + 64 < kend) ATTN_STAGE(cur ^ 1, kt + 64);

        // ---- S^T = K Q^T : lane holds S[q=q5][k = kb*32 + (r&3)+8*(r>>2)+4*hi]
        const char* kb_ = smem + cur * 8192;
        f32x16 s0 = {}, s1 = {};
#pragma unroll
        for (int dc = 0; dc < 4; ++dc) {
            bf16x8 kf0 = *(const bf16x8*)(kb_ + swz(q5, dc * 32 + hi * 16));
            bf16x8 kf1 = *(const bf16x8*)(kb_ + swz(32 + q5, dc * 32 + hi * 16));
            __builtin_amdgcn_s_setprio(1);
            s0 = MFMA32(kf0, qf[dc], s0);
            s1 = MFMA32(kf1, qf[dc], s1);
            __builtin_amdgcn_s_setprio(0);
        }

        // ---- in-lane softmax (exp2 domain) ----
        float t[16];
#pragma unroll
        for (int r = 0; r < 16; ++r) t[r] = fmaxf(s0[r], s1[r]);
#pragma unroll
        for (int d = 8; d >= 1; d >>= 1)
#pragma unroll
            for (int r = 0; r < d; ++r) t[r] = fmaxf(t[r], t[r + d]);
        float pm = fmaxf(t[0], __shfl_xor(t[0], 32));

        if (__any(pm - m_r > 11.5f)) {  // defer-max (2^11.5 ~ e^8)
            float mn = fmaxf(m_r, pm);
            float alv = fexp2(m_r - mn);
            m_r = mn;
            *(float*)(albase + q5 * 4) = alv;
            WAIT_LGKM0();
            f32x4 alr[4];
#pragma unroll
            for (int rg = 0; rg < 4; ++rg)
                alr[rg] = *(const f32x4*)(albase + hi * 16 + rg * 32);
#pragma unroll
            for (int r = 0; r < 16; ++r) {
                oa[0][r] *= alr[r >> 2][r & 3];
                oa[1][r] *= alr[r >> 2][r & 3];
            }
            l_r *= alv;
        }

        float rs = 0.f;
#pragma unroll
        for (int r = 0; r < 16; ++r) {
            float p0 = fexp2(s0[r] - m_r);
            float p1 = fexp2(s1[r] - m_r);
            s0[r] = p0; s1[r] = p1;
            rs += p0 + p1;
        }
        rs += __shfl_xor(rs, 32);
        l_r += rs;

        // ---- P -> bf16 PV A-frags in registers (16 cvt_pk + 8 permlane) ----
        PB pf[4];
#pragma unroll
        for (int kb = 0; kb < 2; ++kb) {
#pragma unroll
            for (int cc = 0; cc < 2; ++cc) {
                int gA = 8 * cc, gB = 8 * cc + 4;
                float a0, a1, a2, a3, b0, b1, b2, b3;
                if (kb == 0) {
                    a0 = s0[gA]; a1 = s0[gA + 1]; a2 = s0[gA + 2]; a3 = s0[gA + 3];
                    b0 = s0[gB]; b1 = s0[gB + 1]; b2 = s0[gB + 2]; b3 = s0[gB + 3];
                } else {
                    a0 = s1[gA]; a1 = s1[gA + 1]; a2 = s1[gA + 2]; a3 = s1[gA + 3];
                    b0 = s1[gB]; b1 = s1[gB + 1]; b2 = s1[gB + 2]; b3 = s1[gB + 3];
                }
                unsigned w0A = cvtpk(a0, a1), w1A = cvtpk(a2, a3);
                unsigned w0B = cvtpk(b0, b1), w1B = cvtpk(b2, b3);
                PSWAP(w0A, w0B);
                PSWAP(w1A, w1B);
                int kc = 2 * kb + cc;
                pf[kc].u[0] = w0A; pf[kc].u[1] = w1A;
                pf[kc].u[2] = w0B; pf[kc].u[3] = w1B;
            }
        }

        // ---- O += P V : B-frags from V^T tile (row = d, col = k) ----
        const char* vb_ = smem + 16384 + cur * 8192;
#pragma unroll
        for (int kc = 0; kc < 4; ++kc) {
            bf16x8 vf0 = *(const bf16x8*)(vb_ + swz(q5, kc * 32 + hi * 16));
            bf16x8 vf1 = *(const bf16x8*)(vb_ + swz(32 + q5, kc * 32 + hi * 16));
            __builtin_amdgcn_s_setprio(1);
            oa[0] = MFMA32(pf[kc].v, vf0, oa[0]);
            oa[1] = MFMA32(pf[kc].v, vf1, oa[1]);
            __builtin_amdgcn_s_setprio(0);
        }

        // barrier: all reads of buf cur done; implicit vmcnt(0) drain also
        // guarantees the prefetch into buf cur^1 has landed.
        __syncthreads();
    }

    // ---- epilogue: locally-normalized partial + (m,l) ----
    {
        float invl = 1.f / l_r;
        *(float*)(albase + q5 * 4) = invl;
        WAIT_LGKM0();
        f32x4 ivr[4];
#pragma unroll
        for (int rg = 0; rg < 4; ++rg)
            ivr[rg] = *(const f32x4*)(albase + hi * 16 + rg * 32);
        __bf16* Opb = half ? Op1 : Op0;
        const size_t rr = (size_t)(b * 8 + h) * 2048;
#pragma unroll
        for (int rg = 0; rg < 4; ++rg)
#pragma unroll
            for (int c = 0; c < 4; ++c) {
                int qr = qt0 + w * 32 + 8 * rg + 4 * hi + c;
                float iv = ivr[rg][c];
                Opb[(rr + qr) * 64 + q5]      = (__bf16)(oa[0][4 * rg + c] * iv);
                Opb[(rr + qr) * 64 + 32 + q5] = (__bf16)(oa[1][4 * rg + c] * iv);
            }
        if (hi == 0) {
            size_t mi_ = ((size_t)half * 65536 + rr + qt0 + w * 32 + q5) * 2;
            ml[mi_] = m_r;
            ml[mi_ + 1] = l_r;
        }
    }
#undef ATTN_STAGE
}

// merge the two KV-halves: O = (w0*O0 + w1*O1), w_h ∝ l_h * 2^(m_h - M)
__global__ __launch_bounds__(256) void attn_merge(const __bf16* __restrict__ Op0,
                                                  const __bf16* __restrict__ Op1,
                                                  const float* __restrict__ ml,
                                                  __bf16* __restrict__ attnb) {
    const int NR = 65536;
    int r = blockIdx.x * 4 + (threadIdx.x >> 6);
    int d = threadIdx.x & 63;
    float m0 = ml[(size_t)r * 2], l0 = ml[(size_t)r * 2 + 1];
    float m1 = ml[((size_t)NR + r) * 2], l1 = ml[((size_t)NR + r) * 2 + 1];
    float M = fmaxf(m0, m1);
    float w0 = fexp2(m0 - M) * l0;
    float w1 = fexp2(m1 - M) * l1;
    float inv = 1.f / (w0 + w1);
    w0 *= inv; w1 *= inv;
    float o0 = (float)Op0[(size_t)r * 64 + d];
    float o1 = (float)Op1[(size_t)r * 64 + d];
    int q = r & 2047, bh = r >> 11, hh = bh & 7, bb = bh >> 3;
    attnb[((size_t)bb * 2048 + q) * 512 + hh * 64 + d] = (__bf16)(o0 * w0 + o1 * w1);
}

extern "C" void kernel_launch(void* const* d_in, const int* in_sizes, int n_in,
                              void* d_out, int out_size, void* d_ws, size_t ws_size,
                              hipStream_t stream) {
    const float* x  = (const float*)d_in[0];
    const float* wq = (const float*)d_in[1];
    const float* bq = (const float*)d_in[2];
    const float* wk = (const float*)d_in[3];
    const float* bk = (const float*)d_in[4];
    const float* wv = (const float*)d_in[5];
    const float* bv = (const float*)d_in[6];
    const float* wo = (const float*)d_in[7];
    const float* bo = (const float*)d_in[8];

    char* ws = (char*)d_ws;
    __bf16* xb    = (__bf16*)(ws);                       // 8 MiB; dead after qkv
    __bf16* Op0   = (__bf16*)(ws);                       // reuses xb region
    __bf16* Qb    = (__bf16*)(ws + ((size_t)8 << 20));
    __bf16* Kb    = (__bf16*)(ws + ((size_t)16 << 20));
    __bf16* Vtb   = (__bf16*)(ws + ((size_t)24 << 20));  // V^T [b][512][2048]
    __bf16* attnb = (__bf16*)(ws + ((size_t)32 << 20));
    __bf16* wqb   = (__bf16*)(ws + ((size_t)40 << 20));
    __bf16* wkb   = (__bf16*)(ws + ((size_t)40 << 20) + ((size_t)512 << 10));
    __bf16* wvb   = (__bf16*)(ws + ((size_t)40 << 20) + ((size_t)1024 << 10));
    __bf16* wob   = (__bf16*)(ws + ((size_t)40 << 20) + ((size_t)1536 << 10));
    __bf16* Op1   = (__bf16*)(ws + ((size_t)42 << 20));  // 8 MiB
    float*  mlb   = (float*)(ws + ((size_t)50 << 20));   // 1 MiB

    cvt_f32_bf16<<<dim3(4096), dim3(256), 0, stream>>>(x, xb, 1048576);
    cvt_w4<<<dim3(256, 4), dim3(256), 0, stream>>>(wq, wk, wv, wo,
                                                   wqb, wkb, wvb, wob);
    qkv_gemm<<<dim3(64, 4, 3), dim3(256), 0, stream>>>(xb, wqb, wkb, wvb,
                                                       bq, bk, bv, Qb, Kb, Vtb);
    attn_fwd<<<dim3(32, 8, 8), dim3(128), 0, stream>>>(Qb, Kb, Vtb, Op0, Op1, mlb);
    attn_merge<<<dim3(16384), dim3(256), 0, stream>>>(Op0, Op1, mlb, attnb);
    out_gemm<<<dim3(64, 8), dim3(256), 0, stream>>>(attnb, wob, bo, (float*)d_out);
}

// Round 9
// 108.420 us; speedup vs baseline: 1.8803x; 1.1096x over previous
//
#include <hip/hip_runtime.h>

typedef __bf16 bf16x8 __attribute__((ext_vector_type(8)));
typedef __bf16 bf16x4 __attribute__((ext_vector_type(4)));
typedef float f32x4 __attribute__((ext_vector_type(4)));
typedef float f32x16 __attribute__((ext_vector_type(16)));

#define MFMA_16x16x32(a, b, c) __builtin_amdgcn_mfma_f32_16x16x32_bf16((a), (b), (c), 0, 0, 0)
#define MFMA32(a, b, c) __builtin_amdgcn_mfma_f32_32x32x16_bf16((a), (b), (c), 0, 0, 0)

#define WAIT_LGKM0() do { \
    asm volatile("s_waitcnt lgkmcnt(0)" ::: "memory"); \
    __builtin_amdgcn_sched_barrier(0); } while (0)

// async global->LDS, 16B per lane; LDS dest must be wave-uniform base + lane*16
typedef const __attribute__((address_space(1))) void GVp;
typedef __attribute__((address_space(3))) void LVp;
#define GLOAD16(gp, lp) \
    __builtin_amdgcn_global_load_lds((GVp*)(gp), (LVp*)(lp), 16, 0, 0)

// 2^x via the HW transcendental (v_exp_f32 IS exp2 on gfx9) — avoids the
// glibc __exp2f macro collision.
__device__ __forceinline__ float fexp2(float x) {
    float r;
    asm("v_exp_f32 %0, %1" : "=v"(r) : "v"(x));
    return r;
}

// pack 2 f32 -> 2 bf16 (RNE) in one u32: low16 = lo, high16 = hi
__device__ __forceinline__ unsigned cvtpk(float lo, float hi) {
    unsigned r;
    asm("v_cvt_pk_bf16_f32 %0, %1, %2" : "=v"(r) : "v"(lo), "v"(hi));
    return r;
}
// swap: a.lanes[32:63] <-> b.lanes[0:31]
#define PSWAP(a, b) asm volatile("v_permlane32_swap_b32 %0, %1" : "+v"(a), "+v"(b))

union PB { unsigned u[4]; bf16x8 v; };

// XOR swizzle for row-major tiles with 128-byte rows
__device__ __forceinline__ int swz(int row, int colb) {
    return row * 128 + (colb ^ ((row & 7) << 4));
}

// ---------------- f32 -> bf16 conversions ----------------
__global__ __launch_bounds__(256) void cvt_f32_bf16(const float* __restrict__ in,
                                                    __bf16* __restrict__ out, int n4) {
    int i = blockIdx.x * 256 + threadIdx.x;
    if (i >= n4) return;
    float4 v = ((const float4*)in)[i];
    bf16x4 o;
    o[0] = (__bf16)v.x; o[1] = (__bf16)v.y; o[2] = (__bf16)v.z; o[3] = (__bf16)v.w;
    ((bf16x4*)out)[i] = o;
}

__global__ __launch_bounds__(256) void cvt_w4(const float* __restrict__ w0,
                                              const float* __restrict__ w1,
                                              const float* __restrict__ w2,
                                              const float* __restrict__ w3,
                                              __bf16* __restrict__ o0,
                                              __bf16* __restrict__ o1,
                                              __bf16* __restrict__ o2,
                                              __bf16* __restrict__ o3) {
    int z = blockIdx.y;
    const float* in = (z == 0) ? w0 : (z == 1) ? w1 : (z == 2) ? w2 : w3;
    __bf16* out = (z == 0) ? o0 : (z == 1) ? o1 : (z == 2) ? o2 : o3;
    int i = blockIdx.x * 256 + threadIdx.x;
    float4 v = ((const float4*)in)[i];
    bf16x4 o;
    o[0] = (__bf16)v.x; o[1] = (__bf16)v.y; o[2] = (__bf16)v.z; o[3] = (__bf16)v.w;
    ((bf16x4*)out)[i] = o;
}

// ---- GEMM body: C[M][N] = (A[M][K] * Bw[N][K]^T + bias[N]) * scale ----
// m97 structure: global_load_lds staging, linear LDS dest, inverse-swizzled
// global source + swizzled reads (rule #21). BN=128: 2x2 waves, 64x64 each.
// BN=64: 4x1 waves, 32x64 each. VT=true: write C^T per-batch (V^T) as
// C_T[b][n][t], b = row>>11.
template <typename OT, bool VT, int BN>
__device__ __forceinline__ void gemm_body(const __bf16* __restrict__ A,
                                          const __bf16* __restrict__ Bw,
                                          const float* __restrict__ bias,
                                          OT* __restrict__ C,
                                          int K, int N, float scale) {
    const int m0 = blockIdx.x * 128;
    const int n0 = blockIdx.y * BN;
    const int tid = threadIdx.x;
    const int l = tid & 63, w = tid >> 6;
    constexpr int MI = (BN == 128) ? 4 : 2;
    constexpr int WMS = (BN == 128) ? 64 : 32;
    const int wr = (BN == 128) ? (w >> 1) : w;
    const int wc = (BN == 128) ? (w & 1) : 0;
    const int lr = l & 15;
    const int lkb = (l >> 4) << 4;

    __shared__ __bf16 As[128 * 64];
    __shared__ __bf16 Bs[BN * 64];
    char* AsC = (char*)As;
    char* BsC = (char*)Bs;

    const int srow = tid >> 3;      // staging row within 32-row group
    const int scol8 = tid & 7;      // staging col group (8 elems)

    f32x4 acc[MI][4] = {};

    for (int k0 = 0; k0 < K; k0 += 64) {
        __syncthreads();
#pragma unroll
        for (int p = 0; p < 4; ++p) {
            int row = p * 32 + srow;
            int c8 = (scol8 ^ (row & 7)) * 8;  // inverse-swizzled source col
            GLOAD16(A + (size_t)(m0 + row) * K + k0 + c8, AsC + p * 4096 + tid * 16);
        }
#pragma unroll
        for (int p = 0; p < BN / 32; ++p) {
            int row = p * 32 + srow;
            int c8 = (scol8 ^ (row & 7)) * 8;
            GLOAD16(Bw + (size_t)(n0 + row) * K + k0 + c8, BsC + p * 4096 + tid * 16);
        }
        __syncthreads();  // compiler drains vmcnt before barrier -> tile ready
#pragma unroll
        for (int kk = 0; kk < 2; ++kk) {
            bf16x8 af[MI], bfr[4];
#pragma unroll
            for (int mi = 0; mi < MI; ++mi)
                af[mi] = *(const bf16x8*)(AsC + swz(wr * WMS + mi * 16 + lr, kk * 64 + lkb));
#pragma unroll
            for (int ni = 0; ni < 4; ++ni)
                bfr[ni] = *(const bf16x8*)(BsC + swz(wc * 64 + ni * 16 + lr, kk * 64 + lkb));
#pragma unroll
            for (int mi = 0; mi < MI; ++mi)
#pragma unroll
                for (int ni = 0; ni < 4; ++ni)
                    acc[mi][ni] = MFMA_16x16x32(af[mi], bfr[ni], acc[mi][ni]);
        }
    }

    const int rb = (l >> 4) * 4;
#pragma unroll
    for (int mi = 0; mi < MI; ++mi) {
#pragma unroll
        for (int ni = 0; ni < 4; ++ni) {
            int gn = n0 + wc * 64 + ni * 16 + lr;
            int gm = m0 + wr * WMS + mi * 16 + rb;
            float bv = bias[gn];
            if constexpr (VT) {
                bf16x4 o4;
#pragma unroll
                for (int j = 0; j < 4; ++j)
                    o4[j] = (__bf16)((acc[mi][ni][j] + bv) * scale);
                *(bf16x4*)((__bf16*)C + ((size_t)(gm >> 11) << 20) +
                           (size_t)gn * 2048 + (gm & 2047)) = o4;
            } else {
#pragma unroll
                for (int j = 0; j < 4; ++j) {
                    float v = (acc[mi][ni][j] + bv) * scale;
                    C[(size_t)(gm + j) * N + gn] = (OT)v;
                }
            }
        }
    }
}

// Q pre-scaled by 0.125 * log2(e): softmax runs in exp2 domain downstream.
#define QSCALE 0.18033688f

__global__ __launch_bounds__(256) void qkv_gemm(const __bf16* __restrict__ X,
                                                const __bf16* __restrict__ Wq,
                                                const __bf16* __restrict__ Wk,
                                                const __bf16* __restrict__ Wv,
                                                const float* __restrict__ bq,
                                                const float* __restrict__ bk,
                                                const float* __restrict__ bv,
                                                __bf16* __restrict__ Qo,
                                                __bf16* __restrict__ Ko,
                                                __bf16* __restrict__ Vto) {
    int z = blockIdx.z;
    if (z == 0) {
        gemm_body<__bf16, false, 128>(X, Wq, bq, Qo, 512, 512, QSCALE);
    } else if (z == 1) {
        gemm_body<__bf16, false, 128>(X, Wk, bk, Ko, 512, 512, 1.0f);
    } else {
        gemm_body<__bf16, true, 128>(X, Wv, bv, Vto, 512, 512, 1.0f);
    }
}

__global__ __launch_bounds__(256) void out_gemm(const __bf16* __restrict__ A,
                                                const __bf16* __restrict__ W,
                                                const float* __restrict__ bias,
                                                float* __restrict__ C) {
    gemm_body<float, false, 64>(A, W, bias, C, 512, 512, 1.0f);
}

// ---------------- flash attention forward, split-KV x2 ----------------
// grid (T/128, H, B*2): b = z>>1, half = z&1. 256 thr = 4 waves, wave owns
// 32 q-rows (QBLK=128). K/V^T tiles in LDS are shared by all 4 waves —
// R8's 2-wave blocks left the CU at 8 waves (VALUBusy 40%, latency-bound);
// 4-wave blocks double residency to 16 waves/CU at the same 33 KB LDS.
// Swapped QK^T (32x32x16), lane-local exp2 softmax, P stays in registers.
// Staging via global_load_lds (async DMA, zero data registers; R7's
// reg-staged prefetch spilled ~450 MB/dispatch). Source addr carries the
// inverse swizzle; reads use swz() (rule #21). The barrier's implicit
// vmcnt(0) drain guarantees the prefetched buffer is complete.
__global__ __launch_bounds__(256, 2) void attn_fwd(const __bf16* __restrict__ Q,
                                                   const __bf16* __restrict__ K,
                                                   const __bf16* __restrict__ Vt,
                                                   __bf16* __restrict__ Op0,
                                                   __bf16* __restrict__ Op1,
                                                   float* __restrict__ ml) {
    const int T = 2048, Cm = 512;
    const int qt0 = blockIdx.x * 128;
    const int h = blockIdx.y;
    const int half = blockIdx.z & 1, b = blockIdx.z >> 1;
    const int kt0 = half * 1024, kend = kt0 + 1024;
    const int tid = threadIdx.x;
    const int l = tid & 63, w = tid >> 6;
    const int q5 = l & 31, hi = l >> 5;
    const size_t rbase = ((size_t)b * T) * Cm + h * 64;                 // Q,K
    const size_t vtbase = ((size_t)b << 20) + (size_t)(h * 64) * 2048;  // Vt

    // [0,16K): K dbuf; [16K,32K): V^T dbuf; [32K,32K+512): al scratch
    __shared__ __align__(16) char smem[33280];

    // staging: 256 thr x 16B x 2 passes per 8KB tile; linear LDS dest
    const int grow = tid >> 3;                       // 0..31
    const int gcol = ((tid & 7) ^ (grow & 7)) * 8;   // inverse-swizzled col
    const __bf16* kgp = K + rbase + (size_t)grow * Cm + gcol;
    const __bf16* vgp = Vt + vtbase + (size_t)grow * 2048 + gcol;

#define ATTN_STAGE(nb, ktv)                                                   \
    do {                                                                      \
        char* kd_ = smem + (nb) * 8192 + tid * 16;                            \
        char* vd_ = smem + 16384 + (nb) * 8192 + tid * 16;                    \
        _Pragma("unroll")                                                     \
        for (int p = 0; p < 2; ++p) {                                         \
            GLOAD16(kgp + (size_t)((ktv) + p * 32) * Cm, kd_ + p * 4096);     \
            GLOAD16(vgp + (size_t)(p * 32) * 2048 + (ktv), vd_ + p * 4096);   \
        }                                                                     \
    } while (0)

    // Q fragments (B-operand): lane holds Q[q5][dc*16 + hi*8 + j]
    bf16x8 qf[4];
#pragma unroll
    for (int dc = 0; dc < 4; ++dc)
        qf[dc] = *(const bf16x8*)(Q + rbase +
            (size_t)(qt0 + w * 32 + q5) * Cm + dc * 16 + hi * 8);

    f32x16 oa[2] = {};
    float m_r = -1e30f, l_r = 0.f;

    // prologue: stage tile kt0 into buffer 0
    ATTN_STAGE(0, kt0);
    __syncthreads();

    char* albase = smem + 32768 + w * 128;

    int cur = 0;
    for (int kt = kt0; kt < kend; kt += 64, cur ^= 1) {
        // async prefetch of next tile into the other buffer (no registers)
        if (kt + 64 < kend) ATTN_STAGE(cur ^ 1, kt + 64);

        // ---- S^T = K Q^T : lane holds S[q=q5][k = kb*32 + (r&3)+8*(r>>2)+4*hi]
        const char* kb_ = smem + cur * 8192;
        f32x16 s0 = {}, s1 = {};
#pragma unroll
        for (int dc = 0; dc < 4; ++dc) {
            bf16x8 kf0 = *(const bf16x8*)(kb_ + swz(q5, dc * 32 + hi * 16));
            bf16x8 kf1 = *(const bf16x8*)(kb_ + swz(32 + q5, dc * 32 + hi * 16));
            __builtin_amdgcn_s_setprio(1);
            s0 = MFMA32(kf0, qf[dc], s0);
            s1 = MFMA32(kf1, qf[dc], s1);
            __builtin_amdgcn_s_setprio(0);
        }

        // ---- in-lane softmax (exp2 domain) ----
        float t[16];
#pragma unroll
        for (int r = 0; r < 16; ++r) t[r] = fmaxf(s0[r], s1[r]);
#pragma unroll
        for (int d = 8; d >= 1; d >>= 1)
#pragma unroll
            for (int r = 0; r < d; ++r) t[r] = fmaxf(t[r], t[r + d]);
        float pm = fmaxf(t[0], __shfl_xor(t[0], 32));

        if (__any(pm - m_r > 11.5f)) {  // defer-max (2^11.5 ~ e^8)
            float mn = fmaxf(m_r, pm);
            float alv = fexp2(m_r - mn);
            m_r = mn;
            *(float*)(albase + q5 * 4) = alv;
            WAIT_LGKM0();
            f32x4 alr[4];
#pragma unroll
            for (int rg = 0; rg < 4; ++rg)
                alr[rg] = *(const f32x4*)(albase + hi * 16 + rg * 32);
#pragma unroll
            for (int r = 0; r < 16; ++r) {
                oa[0][r] *= alr[r >> 2][r & 3];
                oa[1][r] *= alr[r >> 2][r & 3];
            }
            l_r *= alv;
        }

        float rs = 0.f;
#pragma unroll
        for (int r = 0; r < 16; ++r) {
            float p0 = fexp2(s0[r] - m_r);
            float p1 = fexp2(s1[r] - m_r);
            s0[r] = p0; s1[r] = p1;
            rs += p0 + p1;
        }
        rs += __shfl_xor(rs, 32);
        l_r += rs;

        // ---- P -> bf16 PV A-frags in registers (16 cvt_pk + 8 permlane) ----
        PB pf[4];
#pragma unroll
        for (int kb = 0; kb < 2; ++kb) {
#pragma unroll
            for (int cc = 0; cc < 2; ++cc) {
                int gA = 8 * cc, gB = 8 * cc + 4;
                float a0, a1, a2, a3, b0, b1, b2, b3;
                if (kb == 0) {
                    a0 = s0[gA]; a1 = s0[gA + 1]; a2 = s0[gA + 2]; a3 = s0[gA + 3];
                    b0 = s0[gB]; b1 = s0[gB + 1]; b2 = s0[gB + 2]; b3 = s0[gB + 3];
                } else {
                    a0 = s1[gA]; a1 = s1[gA + 1]; a2 = s1[gA + 2]; a3 = s1[gA + 3];
                    b0 = s1[gB]; b1 = s1[gB + 1]; b2 = s1[gB + 2]; b3 = s1[gB + 3];
                }
                unsigned w0A = cvtpk(a0, a1), w1A = cvtpk(a2, a3);
                unsigned w0B = cvtpk(b0, b1), w1B = cvtpk(b2, b3);
                PSWAP(w0A, w0B);
                PSWAP(w1A, w1B);
                int kc = 2 * kb + cc;
                pf[kc].u[0] = w0A; pf[kc].u[1] = w1A;
                pf[kc].u[2] = w0B; pf[kc].u[3] = w1B;
            }
        }

        // ---- O += P V : B-frags from V^T tile (row = d, col = k) ----
        const char* vb_ = smem + 16384 + cur * 8192;
#pragma unroll
        for (int kc = 0; kc < 4; ++kc) {
            bf16x8 vf0 = *(const bf16x8*)(vb_ + swz(q5, kc * 32 + hi * 16));
            bf16x8 vf1 = *(const bf16x8*)(vb_ + swz(32 + q5, kc * 32 + hi * 16));
            __builtin_amdgcn_s_setprio(1);
            oa[0] = MFMA32(pf[kc].v, vf0, oa[0]);
            oa[1] = MFMA32(pf[kc].v, vf1, oa[1]);
            __builtin_amdgcn_s_setprio(0);
        }

        // barrier: all reads of buf cur done; implicit vmcnt(0) drain also
        // guarantees the prefetch into buf cur^1 has landed.
        __syncthreads();
    }

    // ---- epilogue: locally-normalized partial + (m,l) ----
    {
        float invl = 1.f / l_r;
        *(float*)(albase + q5 * 4) = invl;
        WAIT_LGKM0();
        f32x4 ivr[4];
#pragma unroll
        for (int rg = 0; rg < 4; ++rg)
            ivr[rg] = *(const f32x4*)(albase + hi * 16 + rg * 32);
        __bf16* Opb = half ? Op1 : Op0;
        const size_t rr = (size_t)(b * 8 + h) * 2048;
#pragma unroll
        for (int rg = 0; rg < 4; ++rg)
#pragma unroll
            for (int c = 0; c < 4; ++c) {
                int qr = qt0 + w * 32 + 8 * rg + 4 * hi + c;
                float iv = ivr[rg][c];
                Opb[(rr + qr) * 64 + q5]      = (__bf16)(oa[0][4 * rg + c] * iv);
                Opb[(rr + qr) * 64 + 32 + q5] = (__bf16)(oa[1][4 * rg + c] * iv);
            }
        if (hi == 0) {
            size_t mi_ = ((size_t)half * 65536 + rr + qt0 + w * 32 + q5) * 2;
            ml[mi_] = m_r;
            ml[mi_ + 1] = l_r;
        }
    }
#undef ATTN_STAGE
}

// merge the two KV-halves: O = (w0*O0 + w1*O1), w_h ∝ l_h * 2^(m_h - M)
__global__ __launch_bounds__(256) void attn_merge(const __bf16* __restrict__ Op0,
                                                  const __bf16* __restrict__ Op1,
                                                  const float* __restrict__ ml,
                                                  __bf16* __restrict__ attnb) {
    const int NR = 65536;
    int r = blockIdx.x * 4 + (threadIdx.x >> 6);
    int d = threadIdx.x & 63;
    float m0 = ml[(size_t)r * 2], l0 = ml[(size_t)r * 2 + 1];
    float m1 = ml[((size_t)NR + r) * 2], l1 = ml[((size_t)NR + r) * 2 + 1];
    float M = fmaxf(m0, m1);
    float w0 = fexp2(m0 - M) * l0;
    float w1 = fexp2(m1 - M) * l1;
    float inv = 1.f / (w0 + w1);
    w0 *= inv; w1 *= inv;
    float o0 = (float)Op0[(size_t)r * 64 + d];
    float o1 = (float)Op1[(size_t)r * 64 + d];
    int q = r & 2047, bh = r >> 11, hh = bh & 7, bb = bh >> 3;
    attnb[((size_t)bb * 2048 + q) * 512 + hh * 64 + d] = (__bf16)(o0 * w0 + o1 * w1);
}

extern "C" void kernel_launch(void* const* d_in, const int* in_sizes, int n_in,
                              void* d_out, int out_size, void* d_ws, size_t ws_size,
                              hipStream_t stream) {
    const float* x  = (const float*)d_in[0];
    const float* wq = (const float*)d_in[1];
    const float* bq = (const float*)d_in[2];
    const float* wk = (const float*)d_in[3];
    const float* bk = (const float*)d_in[4];
    const float* wv = (const float*)d_in[5];
    const float* bv = (const float*)d_in[6];
    const float* wo = (const float*)d_in[7];
    const float* bo = (const float*)d_in[8];

    char* ws = (char*)d_ws;
    __bf16* xb    = (__bf16*)(ws);                       // 8 MiB; dead after qkv
    __bf16* Op0   = (__bf16*)(ws);                       // reuses xb region
    __bf16* Qb    = (__bf16*)(ws + ((size_t)8 << 20));
    __bf16* Kb    = (__bf16*)(ws + ((size_t)16 << 20));
    __bf16* Vtb   = (__bf16*)(ws + ((size_t)24 << 20));  // V^T [b][512][2048]
    __bf16* attnb = (__bf16*)(ws + ((size_t)32 << 20));
    __bf16* wqb   = (__bf16*)(ws + ((size_t)40 << 20));
    __bf16* wkb   = (__bf16*)(ws + ((size_t)40 << 20) + ((size_t)512 << 10));
    __bf16* wvb   = (__bf16*)(ws + ((size_t)40 << 20) + ((size_t)1024 << 10));
    __bf16* wob   = (__bf16*)(ws + ((size_t)40 << 20) + ((size_t)1536 << 10));
    __bf16* Op1   = (__bf16*)(ws + ((size_t)42 << 20));  // 8 MiB
    float*  mlb   = (float*)(ws + ((size_t)50 << 20));   // 1 MiB

    cvt_f32_bf16<<<dim3(4096), dim3(256), 0, stream>>>(x, xb, 1048576);
    cvt_w4<<<dim3(256, 4), dim3(256), 0, stream>>>(wq, wk, wv, wo,
                                                   wqb, wkb, wvb, wob);
    qkv_gemm<<<dim3(64, 4, 3), dim3(256), 0, stream>>>(xb, wqb, wkb, wvb,
                                                       bq, bk, bv, Qb, Kb, Vtb);
    attn_fwd<<<dim3(16, 8, 8), dim3(256), 0, stream>>>(Qb, Kb, Vtb, Op0, Op1, mlb);
    attn_merge<<<dim3(16384), dim3(256), 0, stream>>>(Op0, Op1, mlb, attnb);
    out_gemm<<<dim3(64, 8), dim3(256), 0, stream>>>(attnb, wob, bo, (float*)d_out);
}